// Round 1
// baseline (467.682 us; speedup 1.0000x reference)
//
#include <hip/hip_runtime.h>

// 3-layer MLP matvec chain, fp32, HBM-bound on weight reads (~435 MB total).
// Roofline floor ~69 us @ 6.3 TB/s; previous structure measured ~452 us
// (~0.96 TB/s) due to 8192 lockstep power-of-two-strided row streams (DRAM
// channel/bank camping) + per-block reduce overhead at 64 KB granularity.
// This version: 1024 long contiguous per-block streams (RPB consecutive rows
// walked linearly), per-block chunk rotation to decorrelate the instantaneous
// address stripe (odd-multiple-of-4KB spread), x staged+squared once into LDS,
// biases pre-folded by an init kernel, per-wave atomicAdd finish (no
// __syncthreads in the hot loop).

__global__ __launch_bounds__(256) void init_bias(
    const float* __restrict__ b1, const float* __restrict__ b2,
    const float* __restrict__ b3,
    float* __restrict__ h1, float* __restrict__ h2, float* __restrict__ out)
{
    const int i = blockIdx.x * 256 + threadIdx.x;
    if (i < 8192)       h1[i] = b1[i];
    else if (i < 16384) h2[i - 8192] = b2[i - 8192];
    else if (i < 17384) out[i - 16384] = b3[i - 16384];
}

// y[row] += dot(W[row,:], f(x))   where f = square if SQ else identity.
// Each block owns RPB consecutive rows => one linear RPB*K*4-byte walk of W.
template<int K, int RPB, int SQ>
__global__ __launch_bounds__(256) void matvec_atomic(
    const float* __restrict__ W,    // nrows x K row-major
    const float* __restrict__ xin,  // K
    float* __restrict__ y)          // nrows, pre-initialized with bias
{
    constexpr int K4     = K / 4;
    constexpr int CHUNKS = K4 / 256;   // 4 KB chunks per row: 4 (K=4096) / 8 (K=8192)

    __shared__ __align__(16) float sx[K];
    const int tid = threadIdx.x;

    // Stage x into LDS once, folding the previous layer's square activation.
    const float4* __restrict__ x4 = (const float4*)xin;
    float4* sx4 = (float4*)sx;
    #pragma unroll
    for (int c = 0; c < CHUNKS; ++c) {
        const int i = c * 256 + tid;
        float4 v = x4[i];
        if (SQ) { v.x *= v.x; v.y *= v.y; v.z *= v.z; v.w *= v.w; }
        sx4[i] = v;
    }
    __syncthreads();

    // Per-block rotation: start the row walk at chunk (b % CHUNKS) so the
    // machine-wide instantaneous address set is spread at an ODD multiple of
    // 4 KB (65x4KB for K=8192/RPB=8) instead of a power-of-two column stripe.
    const int  c0   = blockIdx.x % CHUNKS;
    const long row0 = (long)blockIdx.x * RPB;

    for (int r = 0; r < RPB; ++r) {
        const long row = row0 + r;
        const float4* __restrict__ Wr = (const float4*)(W + row * (long)K);

        float acc = 0.0f;
        #pragma unroll
        for (int j = 0; j < CHUNKS; ++j) {
            int c = c0 + j; if (c >= CHUNKS) c -= CHUNKS;
            const int i = c * 256 + tid;
            const float4 w = Wr[i];
            const float4 v = sx4[i];
            acc += (w.x * v.x + w.y * v.y) + (w.z * v.z + w.w * v.w);
        }

        // wave-64 reduce; one fire-and-forget atomic per wave per row.
        #pragma unroll
        for (int off = 32; off > 0; off >>= 1)
            acc += __shfl_down(acc, off, 64);
        if ((tid & 63) == 0) atomicAdd(&y[row], acc);
    }
}

extern "C" void kernel_launch(void* const* d_in, const int* in_sizes, int n_in,
                              void* d_out, int out_size, void* d_ws, size_t ws_size,
                              hipStream_t stream) {
    const float* x  = (const float*)d_in[0];
    const float* W1 = (const float*)d_in[1];
    const float* b1 = (const float*)d_in[2];
    const float* W2 = (const float*)d_in[3];
    const float* b2 = (const float*)d_in[4];
    const float* W3 = (const float*)d_in[5];
    const float* b3 = (const float*)d_in[6];
    float* out = (float*)d_out;

    float* h1 = (float*)d_ws;          // 8192 floats
    float* h2 = h1 + 8192;             // 8192 floats

    // Fold biases into the accumulators up front.
    init_bias<<<68, 256, 0, stream>>>(b1, b2, b3, h1, h2, out);

    // layer 1: h1 += W1 @ x          (128 MiB, K=4096, 1024 streams of 128 KB)
    matvec_atomic<4096, 8, 0><<<1024, 256, 0, stream>>>(W1, x, h1);
    // layer 2: h2 += W2 @ (h1*h1)    (256 MiB, K=8192, 1024 streams of 256 KB)
    matvec_atomic<8192, 8, 1><<<1024, 256, 0, stream>>>(W2, h1, h2);
    // layer 3: out += W3 @ (h2*h2)   (31 MiB, K=8192, 500 streams of 64 KB)
    matvec_atomic<8192, 2, 1><<<500, 256, 0, stream>>>(W3, h2, out);
}

// Round 2
// 463.810 us; speedup vs baseline: 1.0083x; 1.0083x over previous
//
#include <hip/hip_runtime.h>

// 3-layer MLP matvec chain, fp32. Weight traffic ~435 MB => ~69 us floor
// @6.3 TB/s. R0 (4096 lockstep 2-row blocks) and R1 (1024 long rotated
// streams + LDS x) both measured ~0.95 TB/s aggregate => access-stream shape
// is NOT the limiter. R2 attacks MLP + per-row overhead:
//  - R=4 rows per block accumulated simultaneously (4 independent load
//    chains/lane, x read once per chunk for 4 rows, reduce paid once/block)
//  - zero LDS / zero __syncthreads (x is L1-resident; square applied on READ,
//    so layers store raw W@x+b and the next layer squares while loading)
//  - K-split on layer 3 (1000 blocks) for device-filling parallelism
//  - biases pre-folded by init kernel; per-wave fire-and-forget atomicAdd

__global__ __launch_bounds__(256) void init_bias(
    const float* __restrict__ b1, const float* __restrict__ b2,
    const float* __restrict__ b3,
    float* __restrict__ h1, float* __restrict__ h2, float* __restrict__ out)
{
    const int i = blockIdx.x * 256 + threadIdx.x;
    if (i < 8192)       h1[i] = b1[i];
    else if (i < 16384) h2[i - 8192] = b2[i - 8192];
    else if (i < 17384) out[i - 16384] = b3[i - 16384];
}

// y[row0..row0+R) += W[rows, seg] @ f(x[seg]),  f = square if SQ.
// grid = (nrows/R) * NSEG blocks of 256 threads; COLS = LDK/NSEG.
template<int LDK, int COLS, int R, int NSEG, int SQ>
__global__ __launch_bounds__(256) void matvec(
    const float* __restrict__ W,    // nrows x LDK row-major
    const float* __restrict__ xin,  // LDK (raw pre-activation)
    float* __restrict__ y)          // nrows, pre-initialized with bias
{
    constexpr int C4     = COLS / 4;
    constexpr int CHUNKS = C4 / 256;      // 4-KB chunks per segment
    static_assert(CHUNKS * 256 == C4, "COLS must be multiple of 1024");

    const int tid  = threadIdx.x;
    const int g    = blockIdx.x / NSEG;   // row-group
    const int s    = blockIdx.x - g * NSEG; // K-segment
    const int row0 = g * R;

    const float4* __restrict__ x4 = (const float4*)(xin + (size_t)s * COLS);
    const float4* W4[R];
    #pragma unroll
    for (int r = 0; r < R; ++r)
        W4[r] = (const float4*)(W + (size_t)(row0 + r) * LDK + (size_t)s * COLS);

    float acc[R];
    #pragma unroll
    for (int r = 0; r < R; ++r) acc[r] = 0.0f;

    #pragma unroll
    for (int j = 0; j < CHUNKS; ++j) {
        const int i = j * 256 + tid;      // coalesced: wave covers 1 KB
        float4 v = x4[i];
        if (SQ) { v.x *= v.x; v.y *= v.y; v.z *= v.z; v.w *= v.w; }
        #pragma unroll
        for (int r = 0; r < R; ++r) {
            const float4 w = W4[r][i];
            acc[r] += (w.x * v.x + w.y * v.y) + (w.z * v.z + w.w * v.w);
        }
    }

    // wave-64 butterfly; 4 independent chains interleave to hide DS latency.
    #pragma unroll
    for (int off = 32; off > 0; off >>= 1) {
        #pragma unroll
        for (int r = 0; r < R; ++r)
            acc[r] += __shfl_down(acc[r], off, 64);
    }
    if ((tid & 63) == 0) {
        #pragma unroll
        for (int r = 0; r < R; ++r)
            atomicAdd(&y[row0 + r], acc[r]);
    }
}

extern "C" void kernel_launch(void* const* d_in, const int* in_sizes, int n_in,
                              void* d_out, int out_size, void* d_ws, size_t ws_size,
                              hipStream_t stream) {
    const float* x  = (const float*)d_in[0];
    const float* W1 = (const float*)d_in[1];
    const float* b1 = (const float*)d_in[2];
    const float* W2 = (const float*)d_in[3];
    const float* b2 = (const float*)d_in[4];
    const float* W3 = (const float*)d_in[5];
    const float* b3 = (const float*)d_in[6];
    float* out = (float*)d_out;

    float* h1 = (float*)d_ws;          // 8192 floats, raw W1@x+b1
    float* h2 = h1 + 8192;             // 8192 floats, raw W2@(h1^2)+b2

    init_bias<<<68, 256, 0, stream>>>(b1, b2, b3, h1, h2, out);

    // layer 1: h1 += W1 @ x            (134 MB, 2048 blocks x 64 KB)
    matvec<4096, 4096, 4, 1, 0><<<2048, 256, 0, stream>>>(W1, x, h1);
    // layer 2: h2 += W2 @ (h1*h1)      (268 MB, 2048 blocks x 128 KB)
    matvec<8192, 8192, 4, 1, 1><<<2048, 256, 0, stream>>>(W2, h1, h2);
    // layer 3: out += W3 @ (h2*h2)     (32.8 MB, 1000 blocks x 32 KB, K-split 4)
    matvec<8192, 2048, 4, 4, 1><<<1000, 256, 0, stream>>>(W3, h2, out);
}

// Round 5
// 437.275 us; speedup vs baseline: 1.0695x; 1.0607x over previous
//
#include <hip/hip_runtime.h>

// 3-layer MLP matvec chain, fp32 (~435 MB weights => ~69 us @ 6.3 TB/s floor).
// R0-R2 post-mortem: top-5-by-duration shows ONLY harness 1-GiB fills
// (158-162 us); layer2 (268 MB) never appears => every matvec already
// < 158 us (>= 1.7 TB/s). Three different structures all hit ~452-468 us
// total => timed region is dominated by a fixed harness component (workspace
// poison fills). This round minimizes the controllable part:
//  - one row per WAVE (4 rows/block): one contiguous 16/32-KB stream per
//    wave -- closest mimic of the 6.6 TB/s fill access pattern
//  - nontemporal W loads (zero reuse) so x stays L1/L2-resident
//    (via ext_vector_type alias: __builtin_nontemporal_load rejects
//    HIP_vector_type -- R4 compile fix)
//  - layers 1/2: no atomics, no init kernel -- direct y[row] = acc + bias
//  - out-bias init folded into 4 blocks of the layer-2 kernel
//  - layer 3: K-split (NSEG=8), wave-per-(row,seg), per-wave atomicAdd
// Exactly 3 dispatches total.

typedef float f32x4 __attribute__((ext_vector_type(4)));

// One row per wave. grid = nrows/4 blocks of 256.
template<int K, int SQ, int INIT_OUT>
__global__ __launch_bounds__(256) void matvec_rowwave(
    const float* __restrict__ W,     // nrows x K row-major
    const float* __restrict__ xin,   // K raw pre-activation
    const float* __restrict__ bias,  // nrows
    float* __restrict__ y,           // nrows
    const float* __restrict__ b3,    // 1000 (only if INIT_OUT)
    float* __restrict__ out)         // 1000 (only if INIT_OUT)
{
    constexpr int ITER = K / 4 / 64;   // f32x4 per lane: 16 (4096) / 32 (8192)
    const int tid  = threadIdx.x;
    const int wave = tid >> 6;
    const int lane = tid & 63;
    const int row  = blockIdx.x * 4 + wave;

    const f32x4* __restrict__ W4 = (const f32x4*)(W + (size_t)row * K);
    const f32x4* __restrict__ x4 = (const f32x4*)xin;

    float acc = 0.0f;
    #pragma unroll 8
    for (int j = 0; j < ITER; ++j) {
        const int i = j * 64 + lane;         // wave covers contiguous 1 KB
        const f32x4 w = __builtin_nontemporal_load(&W4[i]);
        f32x4 v = x4[i];
        if (SQ) v *= v;
        acc += (w.x * v.x + w.y * v.y) + (w.z * v.z + w.w * v.w);
    }

    #pragma unroll
    for (int off = 32; off > 0; off >>= 1)
        acc += __shfl_down(acc, off, 64);
    if (lane == 0) y[row] = acc + bias[row];

    if (INIT_OUT && blockIdx.x < 4) {        // seed out with b3 (before layer 3)
        const int i = blockIdx.x * 256 + tid;
        if (i < 1000) out[i] = b3[i];
    }
}

// Layer 3: wave-per-(row, K-segment). grid = (1000/4) * NSEG blocks.
template<int K, int NSEG>
__global__ __launch_bounds__(256) void matvec_l3(
    const float* __restrict__ W,     // 1000 x K row-major
    const float* __restrict__ xin,   // K raw pre-activation (square applied)
    float* __restrict__ out)         // 1000, pre-seeded with b3
{
    constexpr int COLS = K / NSEG;          // 1024
    constexpr int ITER = COLS / 4 / 64;     // 4 f32x4 per lane
    const int tid  = threadIdx.x;
    const int wave = tid >> 6;
    const int lane = tid & 63;
    const int g    = blockIdx.x / NSEG;     // row group
    const int s    = blockIdx.x - g * NSEG; // K segment
    const int row  = g * 4 + wave;

    const f32x4* __restrict__ W4 = (const f32x4*)(W + (size_t)row * K + (size_t)s * COLS);
    const f32x4* __restrict__ x4 = (const f32x4*)(xin + (size_t)s * COLS);

    float acc = 0.0f;
    #pragma unroll
    for (int j = 0; j < ITER; ++j) {
        const int i = j * 64 + lane;
        const f32x4 w = __builtin_nontemporal_load(&W4[i]);
        f32x4 v = x4[i];
        v *= v;
        acc += (w.x * v.x + w.y * v.y) + (w.z * v.z + w.w * v.w);
    }

    #pragma unroll
    for (int off = 32; off > 0; off >>= 1)
        acc += __shfl_down(acc, off, 64);
    if (lane == 0) atomicAdd(&out[row], acc);
}

extern "C" void kernel_launch(void* const* d_in, const int* in_sizes, int n_in,
                              void* d_out, int out_size, void* d_ws, size_t ws_size,
                              hipStream_t stream) {
    const float* x  = (const float*)d_in[0];
    const float* W1 = (const float*)d_in[1];
    const float* b1 = (const float*)d_in[2];
    const float* W2 = (const float*)d_in[3];
    const float* b2 = (const float*)d_in[4];
    const float* W3 = (const float*)d_in[5];
    const float* b3 = (const float*)d_in[6];
    float* out = (float*)d_out;

    float* h1 = (float*)d_ws;          // 8192 floats, raw W1@x+b1
    float* h2 = h1 + 8192;             // 8192 floats, raw W2@(h1^2)+b2

    // layer 1: h1 = W1 @ x + b1          (134 MB, 2048 blocks, wave-per-row)
    matvec_rowwave<4096, 0, 0><<<2048, 256, 0, stream>>>(W1, x, b1, h1, nullptr, nullptr);
    // layer 2: h2 = W2 @ (h1*h1) + b2    (268 MB, 2048 blocks) + seed out=b3
    matvec_rowwave<8192, 1, 1><<<2048, 256, 0, stream>>>(W2, h1, b2, h2, b3, out);
    // layer 3: out += W3 @ (h2*h2)       (33 MB, 2000 blocks, K-split 8)
    matvec_l3<8192, 8><<<2000, 256, 0, stream>>>(W3, h2, out);
}